// Round 4
// baseline (445.695 us; speedup 1.0000x reference)
//
#include <hip/hip_runtime.h>
#include <hip/hip_bf16.h>

typedef short v8s __attribute__((ext_vector_type(8)));
typedef float v4f __attribute__((ext_vector_type(4)));

#define DD 128
#define KTOT 64
#define RANK 16

// ws layout (shorts): P~ [0, 131072) | Q~ [131072, 262144) | W~ [262144, 278528)
// P~/Q~ fragment index: (((kg*8+rr)*4+kk)*64 + lane)*8 + j
//   lane=(q*16+c): k=kg*8+(c&7), r=2*rr+(c>>3), d=(kk*4+q)*8+j
// Step s = kg*2+h covers rr in [h*4, h*4+4) -> shorts [s*8192,(s+1)*8192)
#define QOFF 131072
#define WOFF 262144

__device__ __forceinline__ unsigned int pk_bf16_trunc(float a, float b) {
  return __builtin_amdgcn_perm(__builtin_bit_cast(unsigned int, b),
                               __builtin_bit_cast(unsigned int, a),
                               0x07060302u);
}

__device__ __forceinline__ unsigned short bf16_rne(float x) {
  unsigned int u = __builtin_bit_cast(unsigned int, x);
  u += 0x7FFFu + ((u >> 16) & 1u);
  return (unsigned short)(u >> 16);
}

// ---------------- pre-pass: swizzle weights into B-fragment layout ----------
__global__ __launch_bounds__(256)
void swizzle_weights_kernel(const float* __restrict__ Wl,
                            const float* __restrict__ P,
                            const float* __restrict__ Q,
                            unsigned short* __restrict__ ws) {
  const int tid = blockIdx.x * 256 + threadIdx.x;
  if (tid < 16384) {
    const int kg   = tid >> 11;
    const int rr   = (tid >> 8) & 7;
    const int kk   = (tid >> 6) & 3;
    const int lane = tid & 63;
    const int q = lane >> 4, c = lane & 15;
    const int k = kg * 8 + (c & 7);
    const int r = rr * 2 + (c >> 3);
    const int dbase = (kk * 4 + q) * 8;
    const float* Pg = P + ((long)k * DD) * RANK + r;   // P[k][d][r]
    const float* Qg = Q + ((long)k * DD) * RANK + r;
    union { v8s v; unsigned short h[8]; } po, qo;
#pragma unroll
    for (int j = 0; j < 8; ++j) {
      po.h[j] = bf16_rne(Pg[(long)(dbase + j) * RANK]);
      qo.h[j] = bf16_rne(Qg[(long)(dbase + j) * RANK]);
    }
    *(v8s*)(ws + (long)tid * 8)        = po.v;
    *(v8s*)(ws + QOFF + (long)tid * 8) = qo.v;
  } else if (tid < 16384 + 2048) {
    const int t2   = tid - 16384;
    const int kg   = t2 >> 8;
    const int kk   = (t2 >> 6) & 3;
    const int lane = t2 & 63;
    const int q = lane >> 4, c = lane & 15;
    union { v8s v; unsigned short h[8]; } wo;
#pragma unroll
    for (int j = 0; j < 8; ++j) wo.h[j] = 0;
    if (c < 8) {
      const float* wrow = Wl + (long)(kg * 8 + c) * DD + (kk * 4 + q) * 8;
#pragma unroll
      for (int j = 0; j < 8; ++j) wo.h[j] = bf16_rne(wrow[j]);
    }
    *(v8s*)(ws + WOFF + (long)t2 * 8) = wo.v;
  }
}

// ---------------- main kernel: 512 blocks x 256 rows, all 64 k per block ----
__global__ __launch_bounds__(256, 2)
void antisym_bilinear_kernel(const float* __restrict__ x1,
                             const float* __restrict__ x2,
                             const unsigned short* __restrict__ wsw,
                             float* __restrict__ out) {
  // double-buffered B staging: per step 16KB P + 16KB Q; 2 x 32KB = 64KB
  __shared__ __align__(16) unsigned short lds[2][16384];

  const int b    = blockIdx.x;
  const int tid  = threadIdx.x;
  const int lane = tid & 63;
  const int wave = tid >> 6;
  const int q    = lane >> 4;
  const int c    = lane & 15;

  const int strip0 = b * 16 + wave * 4;

  // ---- prefetch step-0 B data into registers (normal loads -> L2/L3 served)
  v8s pP[4], pQ[4];
#pragma unroll
  for (int i = 0; i < 4; ++i) {
    const int o = (i * 256 + tid) * 8;
    pP[i] = *(const v8s*)(wsw + o);
    pQ[i] = *(const v8s*)(wsw + QOFF + o);
  }

  // ---- A-fragments (persistent): Z = x1-x2, S = x1+x2
  v8s Zf[4][4], Sf[4][4];
#pragma unroll
  for (int t = 0; t < 4; ++t) {
    const int row = (strip0 + t) * 16 + c;       // A: m = lane&15
    const float4* p1 = (const float4*)(x1 + (long)row * DD);
    const float4* p2 = (const float4*)(x2 + (long)row * DD);
#pragma unroll
    for (int kk = 0; kk < 4; ++kk) {
      const int i0 = kk * 8 + q * 2;             // d0 = kk*32 + q*8
      float4 a0 = p1[i0], a1 = p1[i0 + 1];
      float4 b0 = p2[i0], b1 = p2[i0 + 1];
      union { v8s v; unsigned int u[4]; } z, s;
      z.u[0] = pk_bf16_trunc(a0.x - b0.x, a0.y - b0.y);
      z.u[1] = pk_bf16_trunc(a0.z - b0.z, a0.w - b0.w);
      z.u[2] = pk_bf16_trunc(a1.x - b1.x, a1.y - b1.y);
      z.u[3] = pk_bf16_trunc(a1.z - b1.z, a1.w - b1.w);
      s.u[0] = pk_bf16_trunc(a0.x + b0.x, a0.y + b0.y);
      s.u[1] = pk_bf16_trunc(a0.z + b0.z, a0.w + b0.w);
      s.u[2] = pk_bf16_trunc(a1.x + b1.x, a1.y + b1.y);
      s.u[3] = pk_bf16_trunc(a1.z + b1.z, a1.w + b1.w);
      Zf[t][kk] = z.v;
      Sf[t][kk] = s.v;
    }
  }

  for (int kg = 0; kg < 8; ++kg) {
    v8s Wf[4];
#pragma unroll
    for (int kk = 0; kk < 4; ++kk)
      Wf[kk] = *(const v8s*)(wsw + WOFF + (((long)(kg * 4 + kk) * 64 + lane) * 8));

    v4f acc[4];
#pragma unroll
    for (int t = 0; t < 4; ++t) acc[t] = (v4f){0.f, 0.f, 0.f, 0.f};

#pragma unroll
    for (int h = 0; h < 2; ++h) {
      const int s = kg * 2 + h;

      // commit prefetched regs to this step's buffer
      unsigned short* wb = &lds[s & 1][0];
#pragma unroll
      for (int i = 0; i < 4; ++i) {
        const int o = (i * 256 + tid) * 8;
        *(v8s*)(wb + o)        = pP[i];   // ds_write_b128
        *(v8s*)(wb + 8192 + o) = pQ[i];
      }

      // prefetch step s+1 into registers (hides under this step's MFMAs)
      if (s < 15) {
        const unsigned short* gP = wsw + (s + 1) * 8192;
        const unsigned short* gQ = wsw + QOFF + (s + 1) * 8192;
#pragma unroll
        for (int i = 0; i < 4; ++i) {
          const int o = (i * 256 + tid) * 8;
          pP[i] = *(const v8s*)(gP + o);
          pQ[i] = *(const v8s*)(gQ + o);
        }
      }

      __syncthreads();   // one barrier per step (write->read, 2-step reuse gap)

      const unsigned short* bP = wb;
      const unsigned short* bQ = wb + 8192;

#pragma unroll
      for (int rl = 0; rl < 4; ++rl) {
        v8s Pf[4], Qf[4];
#pragma unroll
        for (int kk = 0; kk < 4; ++kk) {
          const int off = ((rl * 4 + kk) * 64 + lane) * 8;
          Pf[kk] = *(const v8s*)(bP + off);   // ds_read_b128
          Qf[kk] = *(const v8s*)(bQ + off);
        }
#pragma unroll
        for (int t = 0; t < 4; ++t) {
          v4f ap = (v4f){0.f, 0.f, 0.f, 0.f};
          v4f aq = (v4f){0.f, 0.f, 0.f, 0.f};
#pragma unroll
          for (int kk = 0; kk < 4; ++kk) {
            ap = __builtin_amdgcn_mfma_f32_16x16x32_bf16(Zf[t][kk], Pf[kk], ap, 0, 0, 0);
            aq = __builtin_amdgcn_mfma_f32_16x16x32_bf16(Sf[t][kk], Qf[kk], aq, 0, 0, 0);
          }
          acc[t] += ap * aq;
        }
      }
    }

    // linear term (W cols 8..15 zero -> lands only in cols 0..7)
#pragma unroll
    for (int t = 0; t < 4; ++t) {
#pragma unroll
      for (int kk = 0; kk < 4; ++kk)
        acc[t] = __builtin_amdgcn_mfma_f32_16x16x32_bf16(Zf[t][kk], Wf[kk], acc[t], 0, 0, 0);
    }

    // epilogue: fold odd-r half (cols 8..15) onto cols 0..7, store
#pragma unroll
    for (int t = 0; t < 4; ++t) {
      float v0 = acc[t][0], v1 = acc[t][1], v2 = acc[t][2], v3 = acc[t][3];
      v0 += __shfl_xor(v0, 8, 64);
      v1 += __shfl_xor(v1, 8, 64);
      v2 += __shfl_xor(v2, 8, 64);
      v3 += __shfl_xor(v3, 8, 64);
      const int row0 = (strip0 + t) * 16 + q * 4;  // C: row = quad*4 + reg
      const int cc = c & 7;
      float* op = out + (long)row0 * KTOT + kg * 8 + cc;
      if (c < 8) { op[0 * KTOT] = v0; op[1 * KTOT] = v1; }
      else       { op[2 * KTOT] = v2; op[3 * KTOT] = v3; }
    }
  }
}

extern "C" void kernel_launch(void* const* d_in, const int* in_sizes, int n_in,
                              void* d_out, int out_size, void* d_ws, size_t ws_size,
                              hipStream_t stream) {
  (void)in_sizes; (void)n_in; (void)ws_size; (void)out_size;
  const float* x1 = (const float*)d_in[0];
  const float* x2 = (const float*)d_in[1];
  const float* Wl = (const float*)d_in[2];
  const float* P  = (const float*)d_in[3];
  const float* Q  = (const float*)d_in[4];
  float* out = (float*)d_out;
  unsigned short* ws = (unsigned short*)d_ws;   // needs 544 KB

  hipLaunchKernelGGL(swizzle_weights_kernel, dim3(72), dim3(256), 0, stream,
                     Wl, P, Q, ws);
  hipLaunchKernelGGL(antisym_bilinear_kernel, dim3(512), dim3(256), 0, stream,
                     x1, x2, ws, out);
}

// Round 5
// 219.721 us; speedup vs baseline: 2.0285x; 2.0285x over previous
//
#include <hip/hip_runtime.h>
#include <hip/hip_bf16.h>

typedef short v8s __attribute__((ext_vector_type(8)));
typedef float v4f __attribute__((ext_vector_type(4)));

#define DD 128
#define KTOT 64
#define RANK 16

// ws layout (shorts): P~ [0, 131072) | Q~ [131072, 262144) | W~ [262144, 278528)
// P~/Q~ fragment index: (((kg*8+rr)*4+kk)*64 + lane)*8 + j
//   lane=(q*16+c): k=kg*8+(c&7), r=2*rr+(c>>3), d=(kk*4+q)*8+j
// Step s = kg*2+h covers rr in [h*4, h*4+4) -> shorts [s*8192,(s+1)*8192)
#define QOFF 131072
#define WOFF 262144

__device__ __forceinline__ unsigned int pk_bf16_trunc(float a, float b) {
  return __builtin_amdgcn_perm(__builtin_bit_cast(unsigned int, b),
                               __builtin_bit_cast(unsigned int, a),
                               0x07060302u);
}

__device__ __forceinline__ unsigned short bf16_rne(float x) {
  unsigned int u = __builtin_bit_cast(unsigned int, x);
  u += 0x7FFFu + ((u >> 16) & 1u);
  return (unsigned short)(u >> 16);
}

// ---------------- pre-pass: swizzle weights into B-fragment layout ----------
__global__ __launch_bounds__(256)
void swizzle_weights_kernel(const float* __restrict__ Wl,
                            const float* __restrict__ P,
                            const float* __restrict__ Q,
                            unsigned short* __restrict__ ws) {
  const int tid = blockIdx.x * 256 + threadIdx.x;
  if (tid < 16384) {
    const int kg   = tid >> 11;
    const int rr   = (tid >> 8) & 7;
    const int kk   = (tid >> 6) & 3;
    const int lane = tid & 63;
    const int q = lane >> 4, c = lane & 15;
    const int k = kg * 8 + (c & 7);
    const int r = rr * 2 + (c >> 3);
    const int dbase = (kk * 4 + q) * 8;
    const float* Pg = P + ((long)k * DD) * RANK + r;   // P[k][d][r]
    const float* Qg = Q + ((long)k * DD) * RANK + r;
    union { v8s v; unsigned short h[8]; } po, qo;
#pragma unroll
    for (int j = 0; j < 8; ++j) {
      po.h[j] = bf16_rne(Pg[(long)(dbase + j) * RANK]);
      qo.h[j] = bf16_rne(Qg[(long)(dbase + j) * RANK]);
    }
    *(v8s*)(ws + (long)tid * 8)        = po.v;
    *(v8s*)(ws + QOFF + (long)tid * 8) = qo.v;
  } else if (tid < 16384 + 2048) {
    const int t2   = tid - 16384;
    const int kg   = t2 >> 8;
    const int kk   = (t2 >> 6) & 3;
    const int lane = t2 & 63;
    const int q = lane >> 4, c = lane & 15;
    union { v8s v; unsigned short h[8]; } wo;
#pragma unroll
    for (int j = 0; j < 8; ++j) wo.h[j] = 0;
    if (c < 8) {
      const float* wrow = Wl + (long)(kg * 8 + c) * DD + (kk * 4 + q) * 8;
#pragma unroll
      for (int j = 0; j < 8; ++j) wo.h[j] = bf16_rne(wrow[j]);
    }
    *(v8s*)(ws + WOFF + (long)t2 * 8) = wo.v;
  }
}

// ---------------- main kernel: 1024 blocks x 128 rows, all 64 k per block ---
// 2 strips/wave keeps unified reg demand ~185 < 256 cap: no spill (R4 lesson).
__global__ __launch_bounds__(256, 2)
void antisym_bilinear_kernel(const float* __restrict__ x1,
                             const float* __restrict__ x2,
                             const unsigned short* __restrict__ wsw,
                             float* __restrict__ out) {
  // double-buffered B staging: per step 16KB P + 16KB Q; 2 x 32KB = 64KB
  __shared__ __align__(16) unsigned short lds[2][16384];

  const int b    = blockIdx.x;
  const int tid  = threadIdx.x;
  const int lane = tid & 63;
  const int wave = tid >> 6;
  const int q    = lane >> 4;
  const int c    = lane & 15;

  const int strip0 = b * 8 + wave * 2;   // 16-row strips; 2 per wave

  // ---- prefetch step-0 B data into registers (normal loads -> L2/L3 served)
  v8s pP[4], pQ[4];
#pragma unroll
  for (int i = 0; i < 4; ++i) {
    const int o = (i * 256 + tid) * 8;
    pP[i] = *(const v8s*)(wsw + o);
    pQ[i] = *(const v8s*)(wsw + QOFF + o);
  }

  // ---- A-fragments (persistent): Z = x1-x2, S = x1+x2
  v8s Zf[2][4], Sf[2][4];
#pragma unroll
  for (int t = 0; t < 2; ++t) {
    const int row = (strip0 + t) * 16 + c;       // A: m = lane&15
    const float4* p1 = (const float4*)(x1 + (long)row * DD);
    const float4* p2 = (const float4*)(x2 + (long)row * DD);
#pragma unroll
    for (int kk = 0; kk < 4; ++kk) {
      const int i0 = kk * 8 + q * 2;             // d0 = kk*32 + q*8
      float4 a0 = p1[i0], a1 = p1[i0 + 1];
      float4 b0 = p2[i0], b1 = p2[i0 + 1];
      union { v8s v; unsigned int u[4]; } z, s;
      z.u[0] = pk_bf16_trunc(a0.x - b0.x, a0.y - b0.y);
      z.u[1] = pk_bf16_trunc(a0.z - b0.z, a0.w - b0.w);
      z.u[2] = pk_bf16_trunc(a1.x - b1.x, a1.y - b1.y);
      z.u[3] = pk_bf16_trunc(a1.z - b1.z, a1.w - b1.w);
      s.u[0] = pk_bf16_trunc(a0.x + b0.x, a0.y + b0.y);
      s.u[1] = pk_bf16_trunc(a0.z + b0.z, a0.w + b0.w);
      s.u[2] = pk_bf16_trunc(a1.x + b1.x, a1.y + b1.y);
      s.u[3] = pk_bf16_trunc(a1.z + b1.z, a1.w + b1.w);
      Zf[t][kk] = z.v;
      Sf[t][kk] = s.v;
    }
  }

#pragma unroll 1   // keep kg rolled: small code, short live ranges, no spill
  for (int kg = 0; kg < 8; ++kg) {
    v4f acc[2];
#pragma unroll
    for (int t = 0; t < 2; ++t) acc[t] = (v4f){0.f, 0.f, 0.f, 0.f};

#pragma unroll
    for (int h = 0; h < 2; ++h) {
      // commit prefetched regs to this step's buffer (buffer index == h)
      unsigned short* wb = &lds[h][0];
#pragma unroll
      for (int i = 0; i < 4; ++i) {
        const int o = (i * 256 + tid) * 8;
        *(v8s*)(wb + o)        = pP[i];   // ds_write_b128
        *(v8s*)(wb + 8192 + o) = pQ[i];
      }

      // prefetch step s+1 into registers (hides under this step's MFMAs)
      const int s = kg * 2 + h;
      if (s < 15) {
        const unsigned short* gP = wsw + (s + 1) * 8192;
        const unsigned short* gQ = wsw + QOFF + (s + 1) * 8192;
#pragma unroll
        for (int i = 0; i < 4; ++i) {
          const int o = (i * 256 + tid) * 8;
          pP[i] = *(const v8s*)(gP + o);
          pQ[i] = *(const v8s*)(gQ + o);
        }
      }

      __syncthreads();   // write->read; reuse of the other buffer is guarded
                         // by the *next* step's barrier (2-step gap)

      const unsigned short* bP = wb;
      const unsigned short* bQ = wb + 8192;

#pragma unroll
      for (int rl = 0; rl < 4; ++rl) {
        v8s Pf[4], Qf[4];
#pragma unroll
        for (int kk = 0; kk < 4; ++kk) {
          const int off = ((rl * 4 + kk) * 64 + lane) * 8;
          Pf[kk] = *(const v8s*)(bP + off);   // ds_read_b128, bank-balanced
          Qf[kk] = *(const v8s*)(bQ + off);
        }
#pragma unroll
        for (int t = 0; t < 2; ++t) {
          v4f ap = (v4f){0.f, 0.f, 0.f, 0.f};
          v4f aq = (v4f){0.f, 0.f, 0.f, 0.f};
#pragma unroll
          for (int kk = 0; kk < 4; ++kk) {
            ap = __builtin_amdgcn_mfma_f32_16x16x32_bf16(Zf[t][kk], Pf[kk], ap, 0, 0, 0);
            aq = __builtin_amdgcn_mfma_f32_16x16x32_bf16(Sf[t][kk], Qf[kk], aq, 0, 0, 0);
          }
          acc[t] += ap * aq;
        }
      }
    }

    // linear term; Wf loaded at point of use (short live range)
    {
      v8s Wf[4];
#pragma unroll
      for (int kk = 0; kk < 4; ++kk)
        Wf[kk] = *(const v8s*)(wsw + WOFF + (((long)(kg * 4 + kk) * 64 + lane) * 8));
#pragma unroll
      for (int t = 0; t < 2; ++t) {
#pragma unroll
        for (int kk = 0; kk < 4; ++kk)
          acc[t] = __builtin_amdgcn_mfma_f32_16x16x32_bf16(Zf[t][kk], Wf[kk], acc[t], 0, 0, 0);
      }
    }

    // epilogue: fold odd-r half (cols 8..15) onto cols 0..7, store
#pragma unroll
    for (int t = 0; t < 2; ++t) {
      float v0 = acc[t][0], v1 = acc[t][1], v2 = acc[t][2], v3 = acc[t][3];
      v0 += __shfl_xor(v0, 8, 64);
      v1 += __shfl_xor(v1, 8, 64);
      v2 += __shfl_xor(v2, 8, 64);
      v3 += __shfl_xor(v3, 8, 64);
      const int row0 = (strip0 + t) * 16 + q * 4;  // C: row = quad*4 + reg
      const int cc = c & 7;
      float* op = out + (long)row0 * KTOT + kg * 8 + cc;
      if (c < 8) { op[0 * KTOT] = v0; op[1 * KTOT] = v1; }
      else       { op[2 * KTOT] = v2; op[3 * KTOT] = v3; }
    }
  }
}

extern "C" void kernel_launch(void* const* d_in, const int* in_sizes, int n_in,
                              void* d_out, int out_size, void* d_ws, size_t ws_size,
                              hipStream_t stream) {
  (void)in_sizes; (void)n_in; (void)ws_size; (void)out_size;
  const float* x1 = (const float*)d_in[0];
  const float* x2 = (const float*)d_in[1];
  const float* Wl = (const float*)d_in[2];
  const float* P  = (const float*)d_in[3];
  const float* Q  = (const float*)d_in[4];
  float* out = (float*)d_out;
  unsigned short* ws = (unsigned short*)d_ws;   // needs 544 KB

  hipLaunchKernelGGL(swizzle_weights_kernel, dim3(72), dim3(256), 0, stream,
                     Wl, P, Q, ws);
  hipLaunchKernelGGL(antisym_bilinear_kernel, dim3(1024), dim3(256), 0, stream,
                     x1, x2, ws, out);
}